// Round 1
// baseline (825.679 us; speedup 1.0000x reference)
//
#include <hip/hip_runtime.h>
#include <math.h>

#define CC 128
#define TN 1000
#define TT 64
#define SPD_EPS 1e-3f
#define RE_EPS 1e-4f

// W21 = W2 @ W1  : (32x64)@(64x128) -> 32x128
__global__ void w21_kernel(const float* __restrict__ W2, const float* __restrict__ W1,
                           float* __restrict__ W21) {
  int idx = blockIdx.x * 256 + threadIdx.x;
  if (idx < 32 * 128) {
    int c = idx >> 7, k = idx & 127;
    float acc = 0.f;
#pragma unroll 8
    for (int m = 0; m < 64; ++m) acc += W2[c * 64 + m] * W1[m * 128 + k];
    W21[idx] = acc;
  }
}

// Per-batch: y = W21 @ x (32 x T), then S2 = cov(y) + eps*I  (32x32)
__global__ __launch_bounds__(256) void cov_kernel(const float* __restrict__ x,
                                                  const float* __restrict__ W21,
                                                  float* __restrict__ S2) {
  const int b = blockIdx.x;
  const int tid = threadIdx.x;
  __shared__ float Ws[32][129];
  __shared__ float ys[TT][34];   // [t][c], padded for conflict-free float2 reads
  __shared__ float ysum_s[32];
  for (int idx = tid; idx < 32 * 128; idx += 256)
    Ws[idx >> 7][idx & 127] = W21[idx];
  const int tg = tid & 15;        // t-group: t0 = tg*4
  const int cp = tid >> 4;        // channel pair base: c in {cp, cp+16}
  const int i0 = (tid >> 4) << 1; // cov 2x2 block row (even)
  const int j0 = (tid & 15) << 1; // cov 2x2 block col (even)
  float a00 = 0.f, a01 = 0.f, a10 = 0.f, a11 = 0.f;
  float ysum = 0.f;
  const float* xb = x + (size_t)b * (CC * TN);
  __syncthreads();
  for (int t0 = 0; t0 < TN; t0 += TT) {
    // ---- projection phase: y[c][t] for this tile, into registers ----
    float acc0[4] = {0.f, 0.f, 0.f, 0.f};
    float acc1[4] = {0.f, 0.f, 0.f, 0.f};
    const int tt = t0 + tg * 4;
    const bool valid = (tt < TN);   // T%4==0 so float4 never straddles
    if (valid) {
      const float* xp = xb + tt;
#pragma unroll 4
      for (int k = 0; k < CC; ++k) {
        const float4 xv = *(const float4*)(xp + k * TN);
        const float w0 = Ws[cp][k];
        const float w1 = Ws[cp + 16][k];
        acc0[0] += w0 * xv.x; acc0[1] += w0 * xv.y;
        acc0[2] += w0 * xv.z; acc0[3] += w0 * xv.w;
        acc1[0] += w1 * xv.x; acc1[1] += w1 * xv.y;
        acc1[2] += w1 * xv.z; acc1[3] += w1 * xv.w;
      }
    }
    __syncthreads();  // previous cov phase done reading ys
#pragma unroll
    for (int v = 0; v < 4; ++v) {
      ys[tg * 4 + v][cp] = valid ? acc0[v] : 0.f;
      ys[tg * 4 + v][cp + 16] = valid ? acc1[v] : 0.f;
    }
    __syncthreads();  // ys ready
    // ---- covariance accumulation phase ----
#pragma unroll 8
    for (int t = 0; t < TT; ++t) {
      const float2 yi = *(const float2*)&ys[t][i0];
      const float2 yj = *(const float2*)&ys[t][j0];
      a00 += yi.x * yj.x; a01 += yi.x * yj.y;
      a10 += yi.y * yj.x; a11 += yi.y * yj.y;
    }
    if (tid < 32) {
      float s = 0.f;
#pragma unroll 8
      for (int t = 0; t < TT; ++t) s += ys[t][tid];
      ysum += s;
    }
  }
  __syncthreads();
  if (tid < 32) ysum_s[tid] = ysum;
  __syncthreads();
  const float inv = 1.f / (float)(TN - 1);
  const float mi0 = ysum_s[i0] / TN, mi1 = ysum_s[i0 + 1] / TN;
  const float mj0 = ysum_s[j0] / TN, mj1 = ysum_s[j0 + 1] / TN;
  float c00 = (a00 - TN * mi0 * mj0) * inv;
  float c01 = (a01 - TN * mi0 * mj1) * inv;
  float c10 = (a10 - TN * mi1 * mj0) * inv;
  float c11 = (a11 - TN * mi1 * mj1) * inv;
  if (i0 == j0) { c00 += SPD_EPS; c11 += SPD_EPS; }
  float* Sb = S2 + ((size_t)b << 10);
  Sb[i0 * 32 + j0] = c00;
  Sb[i0 * 32 + j0 + 1] = c01;
  Sb[(i0 + 1) * 32 + j0] = c10;
  Sb[(i0 + 1) * 32 + j0 + 1] = c11;
}

// Batched 32x32 symmetric eig via parallel-order two-sided Jacobi,
// then reconstruct V * diag(log(max(w,RE_EPS))) * V^T.
// One 64-thread wave per matrix.
__global__ __launch_bounds__(64) void eig_log_kernel(const float* __restrict__ S,
                                                     float* __restrict__ out) {
  const int b = blockIdx.x;
  const int l = threadIdx.x;
  __shared__ float A[32][33];
  __shared__ float V[32][33];
  __shared__ float csc[16], css[16];
  __shared__ float lw[32];
  const float* Sb = S + ((size_t)b << 10);
  for (int idx = l; idx < 1024; idx += 64) {
    int i = idx >> 5, j = idx & 31;
    A[i][j] = Sb[idx];
    V[i][j] = (i == j) ? 1.f : 0.f;
  }
  __syncthreads();
  for (int sweep = 0; sweep < 14; ++sweep) {
    // convergence check: off-diagonal Frobenius^2
    float off = 0.f;
    for (int idx = l; idx < 1024; idx += 64) {
      int i = idx >> 5, j = idx & 31;
      float v = A[i][j];
      if (i != j) off += v * v;
    }
#pragma unroll
    for (int d = 1; d < 64; d <<= 1) off += __shfl_xor(off, d);
    if (off < 1e-10f) break;
    for (int r = 0; r < 31; ++r) {
      // round-robin (circle) pairing: 16 disjoint pairs per round
      if (l < 16) {
        int p, q;
        if (l == 0) { p = 31; q = r % 31; }
        else { p = (r + l) % 31; q = (r + 31 - l) % 31; }
        float app = A[p][p], aqq = A[q][q], apq = A[p][q];
        float c = 1.f, s = 0.f;
        if (fabsf(apq) > 1e-14f) {
          float tau = (aqq - app) / (2.f * apq);
          float t = copysignf(1.f, tau) / (fabsf(tau) + sqrtf(1.f + tau * tau));
          c = 1.f / sqrtf(1.f + t * t);
          s = t * c;
        }
        csc[l] = c; css[l] = s;
      }
      __syncthreads();
      // A <- J^T A (row rotations; pairs disjoint)
      for (int idx = l; idx < 512; idx += 64) {
        int k = idx >> 5, j = idx & 31;
        int p, q;
        if (k == 0) { p = 31; q = r % 31; }
        else { p = (r + k) % 31; q = (r + 31 - k) % 31; }
        float c = csc[k], s = css[k];
        float ap = A[p][j], aq = A[q][j];
        A[p][j] = c * ap - s * aq;
        A[q][j] = s * ap + c * aq;
      }
      __syncthreads();
      // A <- A J, V <- V J (column rotations)
      for (int idx = l; idx < 512; idx += 64) {
        int k = idx >> 5, i = idx & 31;
        int p, q;
        if (k == 0) { p = 31; q = r % 31; }
        else { p = (r + k) % 31; q = (r + 31 - k) % 31; }
        float c = csc[k], s = css[k];
        float ap = A[i][p], aq = A[i][q];
        A[i][p] = c * ap - s * aq;
        A[i][q] = s * ap + c * aq;
        float vp = V[i][p], vq = V[i][q];
        V[i][p] = c * vp - s * vq;
        V[i][q] = s * vp + c * vq;
      }
      __syncthreads();
    }
  }
  if (l < 32) lw[l] = logf(fmaxf(A[l][l], RE_EPS));
  __syncthreads();
  float* Ob = out + ((size_t)b << 10);
  for (int idx = l; idx < 1024; idx += 64) {
    int i = idx >> 5, j = idx & 31;
    float acc = 0.f;
#pragma unroll
    for (int k = 0; k < 32; ++k) acc += V[i][k] * lw[k] * V[j][k];
    Ob[idx] = acc;
  }
}

// out[b][k] = feats[b] . fc_w[k] + fc_b[k]
__global__ void fc_kernel(const float* __restrict__ feats, const float* __restrict__ fcw,
                          const float* __restrict__ fcb, float* __restrict__ out) {
  int idx = blockIdx.x * 256 + threadIdx.x;
  if (idx < 512 * 10) {
    int b = idx / 10, k = idx % 10;
    const float* f = feats + (size_t)b * 1024;
    const float* w = fcw + k * 1024;
    float acc = fcb[k];
#pragma unroll 8
    for (int j = 0; j < 1024; ++j) acc += f[j] * w[j];
    out[idx] = acc;
  }
}

extern "C" void kernel_launch(void* const* d_in, const int* in_sizes, int n_in,
                              void* d_out, int out_size, void* d_ws, size_t ws_size,
                              hipStream_t stream) {
  const float* x   = (const float*)d_in[0];
  const float* W1  = (const float*)d_in[1];
  const float* W2  = (const float*)d_in[2];
  const float* fcw = (const float*)d_in[3];
  const float* fcb = (const float*)d_in[4];
  float* out = (float*)d_out;
  char* ws = (char*)d_ws;
  float* W21  = (float*)ws;                              // 4096 floats
  float* S2   = (float*)(ws + 16384);                    // 512*1024 floats
  float* Slog = (float*)(ws + 16384 + 512 * 1024 * 4);   // 512*1024 floats

  w21_kernel<<<16, 256, 0, stream>>>(W2, W1, W21);
  cov_kernel<<<512, 256, 0, stream>>>(x, W21, S2);
  eig_log_kernel<<<512, 64, 0, stream>>>(S2, Slog);
  fc_kernel<<<20, 256, 0, stream>>>(Slog, fcw, fcb, out);
}

// Round 2
// 531.752 us; speedup vs baseline: 1.5528x; 1.5528x over previous
//
#include <hip/hip_runtime.h>
#include <math.h>

#define CC 128
#define TN 1000
#define TT 64
#define SPD_EPS 1e-3f
#define RE_EPS 1e-4f
#define INV_C 0.86956521739f   // 1/1.15
#define LOG_C 0.13976194238f   // log(1.15)

// W21 = W2 @ W1  : (32x64)@(64x128) -> 32x128
__global__ void w21_kernel(const float* __restrict__ W2, const float* __restrict__ W1,
                           float* __restrict__ W21) {
  int idx = blockIdx.x * 256 + threadIdx.x;
  if (idx < 32 * 128) {
    int c = idx >> 7, k = idx & 127;
    float acc = 0.f;
#pragma unroll 8
    for (int m = 0; m < 64; ++m) acc += W2[c * 64 + m] * W1[m * 128 + k];
    W21[idx] = acc;
  }
}

// Per-batch: y = W21 @ x (32 x T), then S2 = cov(y) + eps*I  (32x32)
__global__ __launch_bounds__(256) void cov_kernel(const float* __restrict__ x,
                                                  const float* __restrict__ W21,
                                                  float* __restrict__ S2) {
  const int b = blockIdx.x;
  const int tid = threadIdx.x;
  __shared__ float Ws[32][129];
  __shared__ float ys[TT][34];
  __shared__ float ysum_s[32];
  for (int idx = tid; idx < 32 * 128; idx += 256)
    Ws[idx >> 7][idx & 127] = W21[idx];
  const int tg = tid & 15;
  const int cp = tid >> 4;
  const int i0 = (tid >> 4) << 1;
  const int j0 = (tid & 15) << 1;
  float a00 = 0.f, a01 = 0.f, a10 = 0.f, a11 = 0.f;
  float ysum = 0.f;
  const float* xb = x + (size_t)b * (CC * TN);
  __syncthreads();
  for (int t0 = 0; t0 < TN; t0 += TT) {
    float acc0[4] = {0.f, 0.f, 0.f, 0.f};
    float acc1[4] = {0.f, 0.f, 0.f, 0.f};
    const int tt = t0 + tg * 4;
    const bool valid = (tt < TN);
    if (valid) {
      const float* xp = xb + tt;
#pragma unroll 4
      for (int k = 0; k < CC; ++k) {
        const float4 xv = *(const float4*)(xp + k * TN);
        const float w0 = Ws[cp][k];
        const float w1 = Ws[cp + 16][k];
        acc0[0] += w0 * xv.x; acc0[1] += w0 * xv.y;
        acc0[2] += w0 * xv.z; acc0[3] += w0 * xv.w;
        acc1[0] += w1 * xv.x; acc1[1] += w1 * xv.y;
        acc1[2] += w1 * xv.z; acc1[3] += w1 * xv.w;
      }
    }
    __syncthreads();
#pragma unroll
    for (int v = 0; v < 4; ++v) {
      ys[tg * 4 + v][cp] = valid ? acc0[v] : 0.f;
      ys[tg * 4 + v][cp + 16] = valid ? acc1[v] : 0.f;
    }
    __syncthreads();
#pragma unroll 8
    for (int t = 0; t < TT; ++t) {
      const float2 yi = *(const float2*)&ys[t][i0];
      const float2 yj = *(const float2*)&ys[t][j0];
      a00 += yi.x * yj.x; a01 += yi.x * yj.y;
      a10 += yi.y * yj.x; a11 += yi.y * yj.y;
    }
    if (tid < 32) {
      float s = 0.f;
#pragma unroll 8
      for (int t = 0; t < TT; ++t) s += ys[t][tid];
      ysum += s;
    }
  }
  __syncthreads();
  if (tid < 32) ysum_s[tid] = ysum;
  __syncthreads();
  const float inv = 1.f / (float)(TN - 1);
  const float mi0 = ysum_s[i0] / TN, mi1 = ysum_s[i0 + 1] / TN;
  const float mj0 = ysum_s[j0] / TN, mj1 = ysum_s[j0 + 1] / TN;
  float c00 = (a00 - TN * mi0 * mj0) * inv;
  float c01 = (a01 - TN * mi0 * mj1) * inv;
  float c10 = (a10 - TN * mi1 * mj0) * inv;
  float c11 = (a11 - TN * mi1 * mj1) * inv;
  if (i0 == j0) { c00 += SPD_EPS; c11 += SPD_EPS; }
  float* Sb = S2 + ((size_t)b << 10);
  Sb[i0 * 32 + j0] = c00;
  Sb[i0 * 32 + j0 + 1] = c01;
  Sb[(i0 + 1) * 32 + j0] = c10;
  Sb[(i0 + 1) * 32 + j0 + 1] = c11;
}

// ---------------- Newton-Schulz inverse-scaling-squaring logm ----------------
// One 64-lane wave per 32x32 matrix. Lane (j = l&31, h = l>>5) owns the
// half-column: rows [16h, 16h+16) of column j, in 16 registers.
// Matmul C = A*B: A broadcast from LDS rows (float4), B = full column in regs.

__device__ __forceinline__ void mm_half(float* __restrict__ c,
                                        const float (* __restrict__ A)[36],
                                        const float* __restrict__ bf,
                                        const int r0) {
#pragma unroll
  for (int i = 0; i < 16; ++i) {
    const float4* row = (const float4*)(A[r0 + i]);
    float acc = 0.f;
#pragma unroll
    for (int kk = 0; kk < 8; ++kk) {
      const float4 r = row[kk];
      acc = fmaf(r.x, bf[4 * kk + 0], acc);
      acc = fmaf(r.y, bf[4 * kk + 1], acc);
      acc = fmaf(r.z, bf[4 * kk + 2], acc);
      acc = fmaf(r.w, bf[4 * kk + 3], acc);
    }
    c[i] = acc;
  }
}

// build full 32-column from the two half-columns (lane l and lane l^32)
__device__ __forceinline__ void expand32(float* __restrict__ bf,
                                         const float* __restrict__ v,
                                         const int h) {
#pragma unroll
  for (int i = 0; i < 16; ++i) {
    const float mine = v[i];
    const float other = __shfl_xor(mine, 32);
    bf[i]      = h ? other : mine;   // rows 0..15
    bf[i + 16] = h ? mine  : other;  // rows 16..31
  }
}

__global__ __launch_bounds__(64) void ns_logm_kernel(const float* __restrict__ S,
                                                     float* __restrict__ out) {
  const int b = blockIdx.x;
  const int lane = threadIdx.x;
  const int j = lane & 31;
  const int h = lane >> 5;
  const int r0 = h << 4;
  const bool hd = ((j >> 4) == h);  // diagonal element falls in this half-column
  const int id = j & 15;            // local row index of the diagonal element

  __shared__ float L0[32][36];
  __shared__ float L1[32][36];

  float y[16], z[16], pm[16], bf[32];

  const float* Sb = S + ((size_t)b << 10);
#pragma unroll
  for (int i = 0; i < 16; ++i) y[i] = Sb[(r0 + i) * 32 + j] * INV_C;

  // ---- 3 square-root levels: coupled Newton-Schulz, iters {6,4,4} ----
#pragma unroll 1
  for (int lvl = 0; lvl < 3; ++lvl) {
    const int n = (lvl == 0) ? 6 : 4;
    // special first iteration (Z0 = I): M = 0.5*(3I - A); Y1 = A*M; Z1 = M
#pragma unroll
    for (int i = 0; i < 16; ++i) {
      const float d = (hd && i == id) ? 1.5f : 0.f;
      pm[i] = d - 0.5f * y[i];
    }
#pragma unroll
    for (int i = 0; i < 16; ++i) L0[r0 + i][j] = y[i];
    __syncthreads();
    expand32(bf, pm, h);
    mm_half(y, L0, bf, r0);          // Y1 = A*M
#pragma unroll
    for (int i = 0; i < 16; ++i) z[i] = pm[i];
    __syncthreads();
#pragma unroll 1
    for (int it = 1; it < n; ++it) {
#pragma unroll
      for (int i = 0; i < 16; ++i) L0[r0 + i][j] = z[i];
#pragma unroll
      for (int i = 0; i < 16; ++i) L1[r0 + i][j] = y[i];
      __syncthreads();
      expand32(bf, y, h);
      mm_half(pm, L0, bf, r0);       // P = Z*Y
#pragma unroll
      for (int i = 0; i < 16; ++i) {
        const float d = (hd && i == id) ? 1.5f : 0.f;
        pm[i] = d - 0.5f * pm[i];    // M = 0.5*(3I - P)
      }
      expand32(bf, pm, h);
      mm_half(y, L1, bf, r0);        // Y' = Y*M
      mm_half(z, L0, bf, r0);        // Z' = Z*M   (commuting family)
      __syncthreads();
    }
  }

  // ---- log(I+E) Taylor, degree 7, Horner ----
#pragma unroll
  for (int i = 0; i < 16; ++i) {
    const float d = (hd && i == id) ? 1.f : 0.f;
    pm[i] = y[i] - d;                // E
  }
#pragma unroll
  for (int i = 0; i < 16; ++i) L0[r0 + i][j] = pm[i];
  __syncthreads();
  // T = c6*I + c7*E
#pragma unroll
  for (int i = 0; i < 16; ++i) {
    const float d = (hd && i == id) ? (-1.f / 6.f) : 0.f;
    z[i] = d + (1.f / 7.f) * pm[i];
  }
  const float cs[5] = {0.2f, -0.25f, 1.f / 3.f, -0.5f, 1.f};
#pragma unroll
  for (int s = 0; s < 5; ++s) {
    expand32(bf, z, h);
    mm_half(pm, L0, bf, r0);         // E*T
#pragma unroll
    for (int i = 0; i < 16; ++i) {
      const float d = (hd && i == id) ? cs[s] : 0.f;
      z[i] = d + pm[i];
    }
  }
  expand32(bf, z, h);
  mm_half(y, L0, bf, r0);            // L = E*T  ~= logm(S^(1/8)/ c^(1/8)-ish)

  float* Ob = out + ((size_t)b << 10);
#pragma unroll
  for (int i = 0; i < 16; ++i) {
    const float d = (hd && i == id) ? LOG_C : 0.f;
    Ob[(r0 + i) * 32 + j] = 8.f * y[i] + d;
  }
}

// out[b][k] = feats[b] . fc_w[k] + fc_b[k]
__global__ void fc_kernel(const float* __restrict__ feats, const float* __restrict__ fcw,
                          const float* __restrict__ fcb, float* __restrict__ out) {
  int idx = blockIdx.x * 256 + threadIdx.x;
  if (idx < 512 * 10) {
    int b = idx / 10, k = idx % 10;
    const float* f = feats + (size_t)b * 1024;
    const float* w = fcw + k * 1024;
    float acc = fcb[k];
#pragma unroll 8
    for (int j = 0; j < 1024; ++j) acc += f[j] * w[j];
    out[idx] = acc;
  }
}

extern "C" void kernel_launch(void* const* d_in, const int* in_sizes, int n_in,
                              void* d_out, int out_size, void* d_ws, size_t ws_size,
                              hipStream_t stream) {
  const float* x   = (const float*)d_in[0];
  const float* W1  = (const float*)d_in[1];
  const float* W2  = (const float*)d_in[2];
  const float* fcw = (const float*)d_in[3];
  const float* fcb = (const float*)d_in[4];
  float* out = (float*)d_out;
  char* ws = (char*)d_ws;
  float* W21  = (float*)ws;                              // 4096 floats
  float* S2   = (float*)(ws + 16384);                    // 512*1024 floats
  float* Slog = (float*)(ws + 16384 + 512 * 1024 * 4);   // 512*1024 floats

  w21_kernel<<<16, 256, 0, stream>>>(W2, W1, W21);
  cov_kernel<<<512, 256, 0, stream>>>(x, W21, S2);
  ns_logm_kernel<<<512, 64, 0, stream>>>(S2, Slog);
  fc_kernel<<<20, 256, 0, stream>>>(Slog, fcw, fcb, out);
}

// Round 3
// 461.414 us; speedup vs baseline: 1.7895x; 1.1524x over previous
//
#include <hip/hip_runtime.h>
#include <math.h>

#define TN 1000
#define SPD_EPS 1e-3f
#define RE_EPS 1e-4f
#define INV_C 0.86956521739f   // 1/1.15
#define LOG_C 0.13976194238f   // log(1.15)

#define NCH 4
#define PART_STRIDE 1056       // 1024 Gram + 32 colsum
// ws layout (bytes):
//   W21      @ 0        : 16 KB
//   partials @ 65536    : 512*4*1056*4 = 8,650,752
//   Slog     @ 8716288  : 2 MB

#define SWZ(r) ((((r) >> 1) & 7) << 2)

// W21 = W2 @ W1  : (32x64)@(64x128) -> 32x128
__global__ void w21_kernel(const float* __restrict__ W2, const float* __restrict__ W1,
                           float* __restrict__ W21) {
  int idx = blockIdx.x * 256 + threadIdx.x;
  if (idx < 32 * 128) {
    int c = idx >> 7, k = idx & 127;
    float acc = 0.f;
#pragma unroll 8
    for (int m = 0; m < 64; ++m) acc += W2[c * 64 + m] * W1[m * 128 + k];
    W21[idx] = acc;
  }
}

#define FMAV(av, xk, wc)                    \
  av[0] = fmaf(wc, xk.x, av[0]);            \
  av[1] = fmaf(wc, xk.y, av[1]);            \
  av[2] = fmaf(wc, xk.z, av[2]);            \
  av[3] = fmaf(wc, xk.w, av[3]);

// One block = (batch, T-chunk of 256). Emits partial Gram A=sum(y y^T) and s=sum(y).
__global__ __launch_bounds__(256) void cov_kernel(const float* __restrict__ x,
                                                  const float* __restrict__ W21g,
                                                  float* __restrict__ partials) {
  const int bid = blockIdx.x;
  const int b = bid >> 2, ch = bid & 3;
  const int tid = threadIdx.x;
  __shared__ float Ws[32 * 128];
  __shared__ float ys[32 * 256];
  for (int idx = tid; idx < 1024; idx += 256)
    ((float4*)Ws)[idx] = ((const float4*)W21g)[idx];
  const int w = tid >> 6;        // wave: channels 8w..8w+7
  const int tl = tid & 63;       // t-quad within chunk
  const int nq = (ch == 3) ? 58 : 64;   // valid quads (last chunk = 232 t)
  const bool valid = tl < nq;
  const float* xb = x + (size_t)b * (128 * TN) + ch * 256 + tl * 4;
  float acc[8][4];
#pragma unroll
  for (int c = 0; c < 8; ++c)
#pragma unroll
    for (int v = 0; v < 4; ++v) acc[c][v] = 0.f;
  __syncthreads();
  const float4 zero4 = make_float4(0.f, 0.f, 0.f, 0.f);
  for (int k = 0; k < 128; k += 4) {
    float4 xv0 = valid ? *(const float4*)(xb + (size_t)(k + 0) * TN) : zero4;
    float4 xv1 = valid ? *(const float4*)(xb + (size_t)(k + 1) * TN) : zero4;
    float4 xv2 = valid ? *(const float4*)(xb + (size_t)(k + 2) * TN) : zero4;
    float4 xv3 = valid ? *(const float4*)(xb + (size_t)(k + 3) * TN) : zero4;
#pragma unroll
    for (int c = 0; c < 8; ++c) {
      const float4 wv = *(const float4*)&Ws[(8 * w + c) * 128 + k];  // wave-uniform broadcast
      FMAV(acc[c], xv0, wv.x);
      FMAV(acc[c], xv1, wv.y);
      FMAV(acc[c], xv2, wv.z);
      FMAV(acc[c], xv3, wv.w);
    }
  }
  // ---- column-sum reduce (registers only) ----
  float ls[8];
#pragma unroll
  for (int c = 0; c < 8; ++c) ls[c] = acc[c][0] + acc[c][1] + acc[c][2] + acc[c][3];
#pragma unroll
  for (int d = 1; d < 64; d <<= 1) {
#pragma unroll
    for (int c = 0; c < 8; ++c) ls[c] += __shfl_xor(ls[c], d);
  }
  float* Pb = partials + (size_t)bid * PART_STRIDE;
  if (tl == 0) {
#pragma unroll
    for (int c = 0; c < 8; ++c) Pb[1024 + 8 * w + c] = ls[c];
  }
  // ---- write y tile to LDS (swizzled, row-contiguous b128) ----
#pragma unroll
  for (int c = 0; c < 8; ++c) {
    const int row = 8 * w + c;
    *(float4*)&ys[row * 256 + ((tl * 4) ^ SWZ(row))] =
        make_float4(acc[c][0], acc[c][1], acc[c][2], acc[c][3]);
  }
  __syncthreads();
  // ---- Gram accumulation: thread owns 2x2 block (i0,j0) ----
  const int i0 = (tid >> 4) << 1;
  const int j0 = (tid & 15) << 1;
  const float* ri0 = ys + i0 * 256;
  const float* ri1 = ys + (i0 + 1) * 256;
  const float* rj0 = ys + j0 * 256;
  const float* rj1 = ys + (j0 + 1) * 256;
  float a00 = 0.f, a01 = 0.f, a10 = 0.f, a11 = 0.f;
#pragma unroll 4
  for (int q = 0; q < 64; ++q) {
    const int t = q * 4;
    const float4 yi0 = *(const float4*)(ri0 + (t ^ SWZ(i0)));
    const float4 yi1 = *(const float4*)(ri1 + (t ^ SWZ(i0 + 1)));
    const float4 yj0 = *(const float4*)(rj0 + (t ^ SWZ(j0)));
    const float4 yj1 = *(const float4*)(rj1 + (t ^ SWZ(j0 + 1)));
    a00 += yi0.x * yj0.x + yi0.y * yj0.y + yi0.z * yj0.z + yi0.w * yj0.w;
    a01 += yi0.x * yj1.x + yi0.y * yj1.y + yi0.z * yj1.z + yi0.w * yj1.w;
    a10 += yi1.x * yj0.x + yi1.y * yj0.y + yi1.z * yj0.z + yi1.w * yj0.w;
    a11 += yi1.x * yj1.x + yi1.y * yj1.y + yi1.z * yj1.z + yi1.w * yj1.w;
  }
  *(float2*)&Pb[i0 * 32 + j0] = make_float2(a00, a01);
  *(float2*)&Pb[(i0 + 1) * 32 + j0] = make_float2(a10, a11);
}

// ---------------- Newton-Schulz inverse-scaling-squaring logm ----------------
__device__ __forceinline__ void mm_half(float* __restrict__ c,
                                        const float (* __restrict__ A)[36],
                                        const float* __restrict__ bf,
                                        const int r0) {
#pragma unroll
  for (int i = 0; i < 16; ++i) {
    const float4* row = (const float4*)(A[r0 + i]);
    float acc = 0.f;
#pragma unroll
    for (int kk = 0; kk < 8; ++kk) {
      const float4 r = row[kk];
      acc = fmaf(r.x, bf[4 * kk + 0], acc);
      acc = fmaf(r.y, bf[4 * kk + 1], acc);
      acc = fmaf(r.z, bf[4 * kk + 2], acc);
      acc = fmaf(r.w, bf[4 * kk + 3], acc);
    }
    c[i] = acc;
  }
}

__device__ __forceinline__ void expand32(float* __restrict__ bf,
                                         const float* __restrict__ v,
                                         const int h) {
#pragma unroll
  for (int i = 0; i < 16; ++i) {
    const float mine = v[i];
    const float other = __shfl_xor(mine, 32);
    bf[i]      = h ? other : mine;
    bf[i + 16] = h ? mine  : other;
  }
}

__global__ __launch_bounds__(64) void ns_logm_kernel(const float* __restrict__ partials,
                                                     float* __restrict__ out) {
  const int b = blockIdx.x;
  const int lane = threadIdx.x;
  const int j = lane & 31;
  const int h = lane >> 5;
  const int r0 = h << 4;
  const bool hd = ((j >> 4) == h);
  const int id = j & 15;

  __shared__ float L0[32][36];
  __shared__ float L1[32][36];
  __shared__ float s_sh[32];

  float y[16], z[16], pm[16], bf[32];

  const float* Pb = partials + (size_t)b * (NCH * PART_STRIDE);
  // combine column sums
  if (lane < 32) {
    float s = 0.f;
#pragma unroll
    for (int c = 0; c < NCH; ++c) s += Pb[c * PART_STRIDE + 1024 + lane];
    s_sh[lane] = s;
  }
  __syncthreads();
  // build S = ((sum A) - s s^T / T) / (T-1) + eps I, pre-scaled by 1/c
#pragma unroll
  for (int i = 0; i < 16; ++i) {
    const int row = r0 + i;
    float A = 0.f;
#pragma unroll
    for (int c = 0; c < NCH; ++c) A += Pb[c * PART_STRIDE + row * 32 + j];
    float cov = (A - s_sh[row] * s_sh[j] * (1.f / TN)) * (1.f / (TN - 1));
    if (row == j) cov += SPD_EPS;
    y[i] = cov * INV_C;
  }

  // ---- 3 sqrt levels: coupled Newton-Schulz, iters {6,4,4} ----
#pragma unroll 1
  for (int lvl = 0; lvl < 3; ++lvl) {
    const int n = (lvl == 0) ? 6 : 4;
#pragma unroll
    for (int i = 0; i < 16; ++i) {
      const float d = (hd && i == id) ? 1.5f : 0.f;
      pm[i] = d - 0.5f * y[i];
    }
#pragma unroll
    for (int i = 0; i < 16; ++i) L0[r0 + i][j] = y[i];
    __syncthreads();
    expand32(bf, pm, h);
    mm_half(y, L0, bf, r0);
#pragma unroll
    for (int i = 0; i < 16; ++i) z[i] = pm[i];
    __syncthreads();
#pragma unroll 1
    for (int it = 1; it < n; ++it) {
#pragma unroll
      for (int i = 0; i < 16; ++i) L0[r0 + i][j] = z[i];
#pragma unroll
      for (int i = 0; i < 16; ++i) L1[r0 + i][j] = y[i];
      __syncthreads();
      expand32(bf, y, h);
      mm_half(pm, L0, bf, r0);
#pragma unroll
      for (int i = 0; i < 16; ++i) {
        const float d = (hd && i == id) ? 1.5f : 0.f;
        pm[i] = d - 0.5f * pm[i];
      }
      expand32(bf, pm, h);
      mm_half(y, L1, bf, r0);
      mm_half(z, L0, bf, r0);
      __syncthreads();
    }
  }

  // ---- log(I+E), degree-7 Taylor (Horner) ----
#pragma unroll
  for (int i = 0; i < 16; ++i) {
    const float d = (hd && i == id) ? 1.f : 0.f;
    pm[i] = y[i] - d;
  }
#pragma unroll
  for (int i = 0; i < 16; ++i) L0[r0 + i][j] = pm[i];
  __syncthreads();
#pragma unroll
  for (int i = 0; i < 16; ++i) {
    const float d = (hd && i == id) ? (-1.f / 6.f) : 0.f;
    z[i] = d + (1.f / 7.f) * pm[i];
  }
  const float cs[5] = {0.2f, -0.25f, 1.f / 3.f, -0.5f, 1.f};
#pragma unroll
  for (int s = 0; s < 5; ++s) {
    expand32(bf, z, h);
    mm_half(pm, L0, bf, r0);
#pragma unroll
    for (int i = 0; i < 16; ++i) {
      const float d = (hd && i == id) ? cs[s] : 0.f;
      z[i] = d + pm[i];
    }
  }
  expand32(bf, z, h);
  mm_half(y, L0, bf, r0);

  float* Ob = out + ((size_t)b << 10);
#pragma unroll
  for (int i = 0; i < 16; ++i) {
    const float d = (hd && i == id) ? LOG_C : 0.f;
    Ob[(r0 + i) * 32 + j] = 8.f * y[i] + d;
  }
}

__global__ void fc_kernel(const float* __restrict__ feats, const float* __restrict__ fcw,
                          const float* __restrict__ fcb, float* __restrict__ out) {
  int idx = blockIdx.x * 256 + threadIdx.x;
  if (idx < 512 * 10) {
    int b = idx / 10, k = idx % 10;
    const float* f = feats + (size_t)b * 1024;
    const float* w = fcw + k * 1024;
    float acc = fcb[k];
#pragma unroll 8
    for (int j = 0; j < 1024; ++j) acc += f[j] * w[j];
    out[idx] = acc;
  }
}

extern "C" void kernel_launch(void* const* d_in, const int* in_sizes, int n_in,
                              void* d_out, int out_size, void* d_ws, size_t ws_size,
                              hipStream_t stream) {
  const float* x   = (const float*)d_in[0];
  const float* W1  = (const float*)d_in[1];
  const float* W2  = (const float*)d_in[2];
  const float* fcw = (const float*)d_in[3];
  const float* fcb = (const float*)d_in[4];
  float* out = (float*)d_out;
  char* ws = (char*)d_ws;
  float* W21      = (float*)ws;                    // 16 KB
  float* partials = (float*)(ws + 65536);          // 8,650,752 B
  float* Slog     = (float*)(ws + 8716288);        // 2 MB

  w21_kernel<<<16, 256, 0, stream>>>(W2, W1, W21);
  cov_kernel<<<512 * NCH, 256, 0, stream>>>(x, W21, partials);
  ns_logm_kernel<<<512, 64, 0, stream>>>(partials, Slog);
  fc_kernel<<<20, 256, 0, stream>>>(Slog, fcw, fcb, out);
}

// Round 4
// 367.871 us; speedup vs baseline: 2.2445x; 1.2543x over previous
//
#include <hip/hip_runtime.h>
#include <hip/hip_bf16.h>
#include <math.h>

#define TN 1000
#define SPD_EPS 1e-3f
#define RE_EPS 1e-4f
#define INV_C 0.86956521739f   // 1/1.15
#define LOG_C 0.13976194238f   // log(1.15)

typedef float f32x16 __attribute__((ext_vector_type(16)));
typedef short bf16x8 __attribute__((ext_vector_type(8)));

// W21 = W2 @ W1  : (32x64)@(64x128) -> 32x128
__global__ void w21_kernel(const float* __restrict__ W2, const float* __restrict__ W1,
                           float* __restrict__ W21) {
  int idx = blockIdx.x * 256 + threadIdx.x;
  if (idx < 32 * 128) {
    int c = idx >> 7, k = idx & 127;
    float acc = 0.f;
#pragma unroll 8
    for (int m = 0; m < 64; ++m) acc += W2[c * 64 + m] * W1[m * 128 + k];
    W21[idx] = acc;
  }
}

__device__ __forceinline__ int tix(int r, int c) {  // r <= c, 4x4 upper-tri tile index
  return r * 4 - (r * (r - 1)) / 2 + (c - r);
}

// One wave per batch. C128 = x x^T via bf16 MFMA (upper 10 tiles), mean-sub+eps,
// then S2 = W21 C W21^T in fp32 through LDS. x is read exactly once, no LDS in hot loop.
__global__ __launch_bounds__(64) void cov_kernel(const float* __restrict__ x,
                                                 const float* __restrict__ W21,
                                                 float* __restrict__ S2) {
  const int b = blockIdx.x;
  const int l = threadIdx.x;
  const int ch = l & 31;
  const int h = l >> 5;

  __shared__ float Ct[10 * 1056];   // 10 tiles [32][33]
  __shared__ float Pl[32 * 130];    // P = W21*C  (32x128, padded)
  __shared__ float s_sh[128];       // column sums

  f32x16 acc00{}, acc01{}, acc02{}, acc03{}, acc11{}, acc12{}, acc13{},
         acc22{}, acc23{}, acc33{};
  float s_own[4] = {0.f, 0.f, 0.f, 0.f};
  bf16x8 fr[4];
  const float* xb = x + (size_t)b * (128 * TN) + (size_t)ch * TN + h * 8;
  float4 sa[8], sb[8];
  const float4 z4 = make_float4(0.f, 0.f, 0.f, 0.f);

  // A-frag of row-block r == B-frag of col-block r: lane holds
  // x[32r + (l&31)][16*kk + (l>>5)*8 + i], i=0..7  (two float4 global loads)
#define LOADS(ST, KK) do {                                                   \
    const bool v_ = (16 * (KK) + 8 * h) < TN;                                \
    _Pragma("unroll")                                                        \
    for (int r_ = 0; r_ < 4; ++r_) {                                         \
      const float* p_ = xb + r_ * 32 * TN + 16 * (KK);                       \
      float4 t0_ = z4, t1_ = z4;                                             \
      if (v_) { t0_ = *(const float4*)p_; t1_ = *(const float4*)(p_ + 4); }  \
      ST[2 * r_] = t0_; ST[2 * r_ + 1] = t1_;                                \
    } } while (0)

#define CONVS(ST) do {                                                       \
    _Pragma("unroll")                                                        \
    for (int r_ = 0; r_ < 4; ++r_) {                                         \
      union { bf16x8 v; __hip_bfloat16 e[8]; } u_;                           \
      const float f_[8] = {ST[2*r_].x, ST[2*r_].y, ST[2*r_].z, ST[2*r_].w,   \
                           ST[2*r_+1].x, ST[2*r_+1].y, ST[2*r_+1].z,         \
                           ST[2*r_+1].w};                                    \
      float ss_ = 0.f;                                                       \
      _Pragma("unroll")                                                      \
      for (int i_ = 0; i_ < 8; ++i_) {                                       \
        u_.e[i_] = __float2bfloat16(f_[i_]); ss_ += f_[i_];                  \
      }                                                                      \
      fr[r_] = u_.v; s_own[r_] += ss_;                                       \
    } } while (0)

#define MFMAS() do {                                                         \
    acc00 = __builtin_amdgcn_mfma_f32_32x32x16_bf16(fr[0], fr[0], acc00, 0, 0, 0); \
    acc01 = __builtin_amdgcn_mfma_f32_32x32x16_bf16(fr[0], fr[1], acc01, 0, 0, 0); \
    acc02 = __builtin_amdgcn_mfma_f32_32x32x16_bf16(fr[0], fr[2], acc02, 0, 0, 0); \
    acc03 = __builtin_amdgcn_mfma_f32_32x32x16_bf16(fr[0], fr[3], acc03, 0, 0, 0); \
    acc11 = __builtin_amdgcn_mfma_f32_32x32x16_bf16(fr[1], fr[1], acc11, 0, 0, 0); \
    acc12 = __builtin_amdgcn_mfma_f32_32x32x16_bf16(fr[1], fr[2], acc12, 0, 0, 0); \
    acc13 = __builtin_amdgcn_mfma_f32_32x32x16_bf16(fr[1], fr[3], acc13, 0, 0, 0); \
    acc22 = __builtin_amdgcn_mfma_f32_32x32x16_bf16(fr[2], fr[2], acc22, 0, 0, 0); \
    acc23 = __builtin_amdgcn_mfma_f32_32x32x16_bf16(fr[2], fr[3], acc23, 0, 0, 0); \
    acc33 = __builtin_amdgcn_mfma_f32_32x32x16_bf16(fr[3], fr[3], acc33, 0, 0, 0); \
  } while (0)

  LOADS(sa, 0);
  int kk = 0;
#pragma unroll 1
  for (; kk < 62; kk += 2) {     // steps 0..61, 1-step prefetch ping-pong
    LOADS(sb, kk + 1);
    CONVS(sa); MFMAS();
    LOADS(sa, kk + 2);
    CONVS(sb); MFMAS();
  }
  CONVS(sa); MFMAS();            // step 62 (tail half masked to zero)

  // ---- column sums -> LDS ----
#pragma unroll
  for (int r = 0; r < 4; ++r) s_own[r] += __shfl_xor(s_own[r], 32);
  if (h == 0) {
#pragma unroll
    for (int r = 0; r < 4; ++r) s_sh[32 * r + ch] = s_own[r];
  }
  __syncthreads();

  // ---- mean-sub + eps, write cov tiles to LDS ----
  // C/D layout: col = lane&31, row = (reg&3) + 8*(reg>>2) + 4*(lane>>5)
#define STORE_T(R_, C_, ACC_) do {                                           \
    float* tp_ = Ct + tix(R_, C_) * 1056;                                    \
    _Pragma("unroll")                                                        \
    for (int p_ = 0; p_ < 16; ++p_) {                                        \
      const int row_ = (p_ & 3) + 8 * (p_ >> 2) + 4 * h;                     \
      const int Rg_ = 32 * (R_) + row_, Cg_ = 32 * (C_) + ch;                \
      float cv_ = (ACC_[p_] - s_sh[Rg_] * s_sh[Cg_] * (1.f / TN))            \
                  * (1.f / (TN - 1));                                        \
      if (Rg_ == Cg_) cv_ += SPD_EPS;                                        \
      tp_[row_ * 33 + ch] = cv_;                                             \
    } } while (0)

  STORE_T(0, 0, acc00); STORE_T(0, 1, acc01); STORE_T(0, 2, acc02);
  STORE_T(0, 3, acc03); STORE_T(1, 1, acc11); STORE_T(1, 2, acc12);
  STORE_T(1, 3, acc13); STORE_T(2, 2, acc22); STORE_T(2, 3, acc23);
  STORE_T(3, 3, acc33);
  __syncthreads();

  // ---- P = W21 * C  (32 x 128): lane owns cols j1=l, j2=64+l ----
  float pa[32], pb[32];
#pragma unroll
  for (int i = 0; i < 32; ++i) { pa[i] = 0.f; pb[i] = 0.f; }
  const int j1 = l, j2 = 64 + l;
  const int c1 = j1 >> 5, c2 = j2 >> 5;
#pragma unroll
  for (int kb = 0; kb < 4; ++kb) {
    const bool u1 = (kb <= c1), u2 = (kb <= c2);
    const int t1 = u1 ? tix(kb, c1) : tix(c1, kb);
    const int t2 = u2 ? tix(kb, c2) : tix(c2, kb);
    const int base1 = t1 * 1056 + (u1 ? (j1 & 31) : (j1 & 31) * 33);
    const int base2 = t2 * 1056 + (u2 ? (j2 & 31) : (j2 & 31) * 33);
    const int st1 = u1 ? 33 : 1;
    const int st2 = u2 ? 33 : 1;
    const float* wp = W21 + kb * 32;
#pragma unroll 1
    for (int k2 = 0; k2 < 32; ++k2) {
      const float cv1 = Ct[base1 + k2 * st1];
      const float cv2 = Ct[base2 + k2 * st2];
#pragma unroll
      for (int i = 0; i < 32; ++i) {
        const float wv = wp[i * 128 + k2];   // wave-uniform -> scalar load
        pa[i] = fmaf(wv, cv1, pa[i]);
        pb[i] = fmaf(wv, cv2, pb[i]);
      }
    }
  }
#pragma unroll
  for (int i = 0; i < 32; ++i) { Pl[i * 130 + j1] = pa[i]; Pl[i * 130 + j2] = pb[i]; }
  __syncthreads();

  // ---- S2 = P * W21^T (32x32): lane (h,ch) owns rows h*16..h*16+15, col ch ----
  float sc[16];
#pragma unroll
  for (int ii = 0; ii < 16; ++ii) sc[ii] = 0.f;
  const float* wr = W21 + ch * 128;
#pragma unroll 1
  for (int k = 0; k < 128; ++k) {
    const float wv = wr[k];
#pragma unroll
    for (int ii = 0; ii < 16; ++ii)
      sc[ii] = fmaf(Pl[(h * 16 + ii) * 130 + k], wv, sc[ii]);
  }
  float* So = S2 + ((size_t)b << 10);
#pragma unroll
  for (int ii = 0; ii < 16; ++ii) So[(h * 16 + ii) * 32 + ch] = sc[ii];
}

// ---------------- Newton-Schulz inverse-scaling-squaring logm ----------------
__device__ __forceinline__ void mm_half(float* __restrict__ c,
                                        const float (* __restrict__ A)[36],
                                        const float* __restrict__ bf,
                                        const int r0) {
#pragma unroll
  for (int i = 0; i < 16; ++i) {
    const float4* row = (const float4*)(A[r0 + i]);
    float acc = 0.f;
#pragma unroll
    for (int kk = 0; kk < 8; ++kk) {
      const float4 r = row[kk];
      acc = fmaf(r.x, bf[4 * kk + 0], acc);
      acc = fmaf(r.y, bf[4 * kk + 1], acc);
      acc = fmaf(r.z, bf[4 * kk + 2], acc);
      acc = fmaf(r.w, bf[4 * kk + 3], acc);
    }
    c[i] = acc;
  }
}

__device__ __forceinline__ void expand32(float* __restrict__ bf,
                                         const float* __restrict__ v,
                                         const int h) {
#pragma unroll
  for (int i = 0; i < 16; ++i) {
    const float mine = v[i];
    const float other = __shfl_xor(mine, 32);
    bf[i]      = h ? other : mine;
    bf[i + 16] = h ? mine  : other;
  }
}

__global__ __launch_bounds__(64) void ns_logm_kernel(const float* __restrict__ S,
                                                     float* __restrict__ out) {
  const int b = blockIdx.x;
  const int lane = threadIdx.x;
  const int j = lane & 31;
  const int h = lane >> 5;
  const int r0 = h << 4;
  const bool hd = ((j >> 4) == h);
  const int id = j & 15;

  __shared__ float L0[32][36];
  __shared__ float L1[32][36];

  float y[16], z[16], pm[16], bf[32];

  const float* Sb = S + ((size_t)b << 10);
#pragma unroll
  for (int i = 0; i < 16; ++i) y[i] = Sb[(r0 + i) * 32 + j] * INV_C;

  // ---- 3 sqrt levels: coupled Newton-Schulz, iters {6,4,4} ----
#pragma unroll 1
  for (int lvl = 0; lvl < 3; ++lvl) {
    const int n = (lvl == 0) ? 6 : 4;
#pragma unroll
    for (int i = 0; i < 16; ++i) {
      const float d = (hd && i == id) ? 1.5f : 0.f;
      pm[i] = d - 0.5f * y[i];
    }
#pragma unroll
    for (int i = 0; i < 16; ++i) L0[r0 + i][j] = y[i];
    __syncthreads();
    expand32(bf, pm, h);
    mm_half(y, L0, bf, r0);
#pragma unroll
    for (int i = 0; i < 16; ++i) z[i] = pm[i];
    __syncthreads();
#pragma unroll 1
    for (int it = 1; it < n; ++it) {
#pragma unroll
      for (int i = 0; i < 16; ++i) L0[r0 + i][j] = z[i];
#pragma unroll
      for (int i = 0; i < 16; ++i) L1[r0 + i][j] = y[i];
      __syncthreads();
      expand32(bf, y, h);
      mm_half(pm, L0, bf, r0);
#pragma unroll
      for (int i = 0; i < 16; ++i) {
        const float d = (hd && i == id) ? 1.5f : 0.f;
        pm[i] = d - 0.5f * pm[i];
      }
      expand32(bf, pm, h);
      mm_half(y, L1, bf, r0);
      mm_half(z, L0, bf, r0);
      __syncthreads();
    }
  }

  // ---- log(I+E), degree-7 Taylor (Horner) ----
#pragma unroll
  for (int i = 0; i < 16; ++i) {
    const float d = (hd && i == id) ? 1.f : 0.f;
    pm[i] = y[i] - d;
  }
#pragma unroll
  for (int i = 0; i < 16; ++i) L0[r0 + i][j] = pm[i];
  __syncthreads();
#pragma unroll
  for (int i = 0; i < 16; ++i) {
    const float d = (hd && i == id) ? (-1.f / 6.f) : 0.f;
    z[i] = d + (1.f / 7.f) * pm[i];
  }
  const float cs[5] = {0.2f, -0.25f, 1.f / 3.f, -0.5f, 1.f};
#pragma unroll
  for (int s = 0; s < 5; ++s) {
    expand32(bf, z, h);
    mm_half(pm, L0, bf, r0);
#pragma unroll
    for (int i = 0; i < 16; ++i) {
      const float d = (hd && i == id) ? cs[s] : 0.f;
      z[i] = d + pm[i];
    }
  }
  expand32(bf, z, h);
  mm_half(y, L0, bf, r0);

  float* Ob = out + ((size_t)b << 10);
#pragma unroll
  for (int i = 0; i < 16; ++i) {
    const float d = (hd && i == id) ? LOG_C : 0.f;
    Ob[(r0 + i) * 32 + j] = 8.f * y[i] + d;
  }
}

// one wave per batch: 10 dot-products of length 1024, lane-split + shuffle reduce
__global__ __launch_bounds__(64) void fc_kernel(const float* __restrict__ feats,
                                                const float* __restrict__ fcw,
                                                const float* __restrict__ fcb,
                                                float* __restrict__ out) {
  const int b = blockIdx.x;
  const int l = threadIdx.x;
  const float* f = feats + (size_t)b * 1024 + l * 16;
  float4 fv[4];
#pragma unroll
  for (int q = 0; q < 4; ++q) fv[q] = *(const float4*)(f + 4 * q);
#pragma unroll 1
  for (int k = 0; k < 10; ++k) {
    const float* w = fcw + (size_t)k * 1024 + l * 16;
    float a = 0.f;
#pragma unroll
    for (int q = 0; q < 4; ++q) {
      const float4 wv = *(const float4*)(w + 4 * q);
      a += fv[q].x * wv.x + fv[q].y * wv.y + fv[q].z * wv.z + fv[q].w * wv.w;
    }
#pragma unroll
    for (int d = 1; d < 64; d <<= 1) a += __shfl_xor(a, d);
    if (l == 0) out[b * 10 + k] = a + fcb[k];
  }
}

extern "C" void kernel_launch(void* const* d_in, const int* in_sizes, int n_in,
                              void* d_out, int out_size, void* d_ws, size_t ws_size,
                              hipStream_t stream) {
  const float* x   = (const float*)d_in[0];
  const float* W1  = (const float*)d_in[1];
  const float* W2  = (const float*)d_in[2];
  const float* fcw = (const float*)d_in[3];
  const float* fcb = (const float*)d_in[4];
  float* out = (float*)d_out;
  char* ws = (char*)d_ws;
  float* W21  = (float*)ws;                      // 16 KB
  float* S2   = (float*)(ws + 65536);            // 2 MB
  float* Slog = (float*)(ws + 65536 + 2097152);  // 2 MB

  w21_kernel<<<16, 256, 0, stream>>>(W2, W1, W21);
  cov_kernel<<<512, 64, 0, stream>>>(x, W21, S2);
  ns_logm_kernel<<<512, 64, 0, stream>>>(S2, Slog);
  fc_kernel<<<512, 64, 0, stream>>>(Slog, fcw, fcb, out);
}